// Round 13
// baseline (125.316 us; speedup 1.0000x reference)
//
#include <hip/hip_runtime.h>
#include <hip/hip_bf16.h>

// Problem constants
constexpr int BATCH = 4;
constexpr int SEQ   = 4096;
constexpr int DIM   = 128;   // head size

// Split-KV: KV tiles are 64 keys; CHUNK tiles per split block (templated).
constexpr size_t QKV_BYTES = (size_t)3 * BATCH * SEQ * DIM * 2;
// partial slot: m[64] f32 (log2 domain), l[64] f32, O[64][128] bf16
constexpr size_t SLOT_BYTES = 64 * 4 + 64 * 4 + 64 * 128 * 2;   // 16896

constexpr int tasks_per_b(int chunk) {
    return chunk * (64 / chunk) * (64 / chunk + 1) / 2;
}
constexpr size_t part_bytes(int chunk) {
    return (size_t)BATCH * tasks_per_b(chunk) * SLOT_BYTES;
}

typedef __bf16 bf16x8 __attribute__((ext_vector_type(8)));
typedef __bf16 bf16x4 __attribute__((ext_vector_type(4)));
typedef float  f32x4  __attribute__((ext_vector_type(4)));

// ---------------------------------------------------------------------------
// Kernel 1: QKV projection, 64-row blocks. Grid (256, 3) = 768 blocks.
// ---------------------------------------------------------------------------
__global__ __launch_bounds__(256) void qkv_proj(
    const float* __restrict__ x,
    const float* __restrict__ Wq, const float* __restrict__ Wk,
    const float* __restrict__ Wv,
    __bf16* __restrict__ q, __bf16* __restrict__ k, __bf16* __restrict__ v)
{
    __shared__ __align__(16) __bf16 Xl[64][136];
    __shared__ __align__(16) __bf16 Wt[128][136];   // W transposed: Wt[d][c]

    const int t    = threadIdx.x;
    const int lane = t & 63;
    const int w    = t >> 6;
    const int l15  = lane & 15;
    const int l4   = lane >> 4;
    const int rowblk = blockIdx.x * 64;
    const int m      = blockIdx.y;

    const float* W  = (m == 0) ? Wq : (m == 1) ? Wk : Wv;
    __bf16*      op = (m == 0) ? q  : (m == 1) ? k  : v;

    #pragma unroll
    for (int i = 0; i < 8; ++i) {
        int idx = i * 256 + t;
        int r   = idx >> 5;
        int c4  = (idx & 31) << 2;
        float4 f = *(const float4*)(x + (size_t)(rowblk + r) * DIM + c4);
        __bf16* dst = &Xl[r][c4];
        dst[0] = (__bf16)f.x; dst[1] = (__bf16)f.y;
        dst[2] = (__bf16)f.z; dst[3] = (__bf16)f.w;
    }
    #pragma unroll
    for (int i = 0; i < 16; ++i) {
        int idx = i * 256 + t;
        int r   = idx >> 5;
        int c4  = (idx & 31) << 2;
        float4 f = *(const float4*)(W + (size_t)r * DIM + c4);
        Wt[c4 + 0][r] = (__bf16)f.x;
        Wt[c4 + 1][r] = (__bf16)f.y;
        Wt[c4 + 2][r] = (__bf16)f.z;
        Wt[c4 + 3][r] = (__bf16)f.w;
    }
    __syncthreads();

    f32x4 acc[8];
    #pragma unroll
    for (int cf = 0; cf < 8; ++cf) acc[cf] = (f32x4){0.f, 0.f, 0.f, 0.f};

    #pragma unroll
    for (int kc = 0; kc < 4; ++kc) {
        bf16x8 af = *(const bf16x8*)&Xl[w * 16 + l15][kc * 32 + l4 * 8];
        #pragma unroll
        for (int cf = 0; cf < 8; ++cf) {
            bf16x8 bfr = *(const bf16x8*)&Wt[cf * 16 + l15][kc * 32 + l4 * 8];
            acc[cf] = __builtin_amdgcn_mfma_f32_16x16x32_bf16(af, bfr, acc[cf], 0, 0, 0);
        }
    }

    #pragma unroll
    for (int cf = 0; cf < 8; ++cf)
        #pragma unroll
        for (int r2 = 0; r2 < 4; ++r2) {
            int row = rowblk + w * 16 + l4 * 4 + r2;
            int col = cf * 16 + l15;
            op[(size_t)row * DIM + col] = (__bf16)acc[cf][r2];
        }
}

// ---------------------------------------------------------------------------
// Kernel 2: causal flash attention, split-KV. R12's structure with:
//  (a) V ones-column: Vt extended to [144][72]; row d=128 = 1.0 (129..143 = 0,
//      init once). PV's df=8 MFMA accumulates row-sums into o8, which receives
//      the same alpha rescale as o -- so o8 ends as l. Removes the rowsum
//      shuffle-reduce (16 add + 16 shfl, half ds_swizzle) and lr bookkeeping.
//  (b) exp2-domain softmax: scale*log2e folded into logits; m is log2-domain
//      (combine uses exp2f accordingly).
//  Everything else identical to R12 (pi-permuted P/V, aliased Pl, setprio).
// ---------------------------------------------------------------------------
template <bool SPLIT, int CHUNK>
__global__ __launch_bounds__(256) void attn(
    const __bf16* __restrict__ q, const __bf16* __restrict__ k,
    const __bf16* __restrict__ v, float* __restrict__ out,
    char* __restrict__ part)
{
    constexpr int NG    = 64 / CHUNK;
    constexpr int TASKS = tasks_per_b(CHUNK);

    __shared__ __align__(16) __bf16 KlBuf[64 * 136];   // Kl in QK^T phase; Pl in PV phase
    __shared__ __align__(16) __bf16 Vt[144][72];       // rows 0..127: V^T; 128: ones

    typedef __bf16 (*KlT)[136];
    typedef __bf16 (*PlT)[16][72];
    KlT Kl = (KlT)KlBuf;            // [64][136]
    PlT Pl = (PlT)KlBuf;            // [4][16][72] = 9216 B

    const int t    = threadIdx.x;
    const int lane = t & 63;
    const int w    = t >> 6;
    const int l15  = lane & 15;
    const int l4   = lane >> 4;
    const int b    = blockIdx.y;

    int qt, chunk, nch, slot = 0;
    if (SPLIT) {
        int j = blockIdx.x;                 // 0..TASKS-1
        int g = 0;
        while (g < NG - 1 && j >= CHUNK * (g + 1) * (g + 2) / 2) ++g;
        int r = j - CHUNK * g * (g + 1) / 2;
        nch   = g + 1;
        qt    = CHUNK * g + r / nch;
        chunk = r - (r / nch) * nch;
        slot  = b * TASKS + j;
    } else {
        qt = blockIdx.x; chunk = 0; nch = 1;
    }
    const int qb0 = qt * 64;
    const int jt0 = chunk * CHUNK;
    const int jtE = SPLIT ? min(jt0 + CHUNK, qt + 1) : qt + 1;
    const size_t base = (size_t)b * SEQ * DIM;

    // init ones/zero rows of Vt (128..143) once; visible after first barrier
    for (int i = t; i < 16 * 72; i += 256) {
        int r0 = i / 72, c0 = i % 72;
        Vt[128 + r0][c0] = (r0 == 0) ? (__bf16)1.0f : (__bf16)0.0f;
    }

    // staging geometry
    const int rr = t >> 4;             // 0..15  (K rows)
    const int c  = (t & 15) * 8;       // K d-base
    const int vp = t >> 5;             // 0..7   (V pair id within group)
    const int vd = (t & 31) * 4;       // V d-base

    // Q fragments (A-operand layout: row = l15, k = l4*8 + j + 32*dc)
    bf16x8 qf[4];
    {
        const __bf16* qrow = q + base + (size_t)(qb0 + w * 16 + l15) * DIM;
        #pragma unroll
        for (int dc = 0; dc < 4; ++dc)
            qf[dc] = *(const bf16x8*)(qrow + dc * 32 + l4 * 8);
    }

    f32x4 o[8], o8;
    #pragma unroll
    for (int i = 0; i < 8; ++i) o[i] = (f32x4){0.f, 0.f, 0.f, 0.f};
    o8 = (f32x4){0.f, 0.f, 0.f, 0.f};
    float mr[4];
    #pragma unroll
    for (int r = 0; r < 4; ++r) mr[r] = -INFINITY;

    // logits scaled by (1/sqrt(128))*log2(e); softmax in exp2 domain
    const float kScaleLog2e = 0.12751744549764568f;

    for (int jt = jt0; jt < jtE; ++jt) {
        __syncthreads();   // B1: all waves done with Pl(=KlBuf)/Vt of prev tile

        // ---- load K (linear, padded) and V (pi-permuted pair-packed) ----
        {
            const __bf16* kg = k + base + (size_t)jt * 64 * DIM;
            const __bf16* vg = v + base + (size_t)jt * 64 * DIM;
            #pragma unroll
            for (int i = 0; i < 4; ++i) {
                int row = i * 16 + rr;
                *(int4*)&Kl[row][c] = *(const int4*)(kg + (size_t)row * DIM + c);
                // V: pair (ka, ka+16) -> adjacent new indices (kn, kn+1)
                int p    = i * 8 + vp;        // pair id 0..31
                int l15_ = p >> 1;
                int kcp  = p & 1;
                int ka   = 32 * kcp + l15_;   // old key (even new slot)
                int kn   = 4 * l15_ + 2 * kcp;// permuted index, even
                ushort4 va = *(const ushort4*)(vg + (size_t)ka * DIM + vd);
                ushort4 vb = *(const ushort4*)(vg + (size_t)(ka + 16) * DIM + vd);
                #pragma unroll
                for (int e = 0; e < 4; ++e) {
                    int cc  = vd + e;                                  // d index
                    int col = (((kn >> 3) ^ ((cc >> 3) & 7)) << 3) | (kn & 7);
                    ushort2 pr;
                    pr.x = (&va.x)[e];
                    pr.y = (&vb.x)[e];
                    *(ushort2*)&Vt[cc][col] = pr;
                }
            }
        }
        __syncthreads();   // B2: Kl/Vt visible

        // ---- S = Q K^T ----
        f32x4 s[4];
        __builtin_amdgcn_s_setprio(1);
        #pragma unroll
        for (int kc = 0; kc < 4; ++kc) {
            f32x4 acc = (f32x4){0.f, 0.f, 0.f, 0.f};
            #pragma unroll
            for (int dc = 0; dc < 4; ++dc) {
                bf16x8 kf = *(const bf16x8*)&Kl[kc * 16 + l15][dc * 32 + l4 * 8];
                acc = __builtin_amdgcn_mfma_f32_16x16x32_bf16(qf[dc], kf, acc, 0, 0, 0);
            }
            s[kc] = acc;
        }
        __builtin_amdgcn_s_setprio(0);

        // ---- scale(+log2e) + causal mask + online max (exp2 domain) ----
        const bool diag = (jt == qt);
        float rowmax[4];
        #pragma unroll
        for (int r = 0; r < 4; ++r) rowmax[r] = -INFINITY;
        #pragma unroll
        for (int kc = 0; kc < 4; ++kc) {
            int key = jt * 64 + kc * 16 + l15;
            #pragma unroll
            for (int r = 0; r < 4; ++r) {
                float sv = s[kc][r] * kScaleLog2e;
                if (diag) {
                    int qrow = qb0 + w * 16 + l4 * 4 + r;
                    if (key > qrow) sv = -INFINITY;
                }
                s[kc][r] = sv;
                rowmax[r] = fmaxf(rowmax[r], sv);
            }
        }
        #pragma unroll
        for (int r = 0; r < 4; ++r) {
            float x2 = rowmax[r];
            x2 = fmaxf(x2, __shfl_xor(x2, 1));
            x2 = fmaxf(x2, __shfl_xor(x2, 2));
            x2 = fmaxf(x2, __shfl_xor(x2, 4));
            x2 = fmaxf(x2, __shfl_xor(x2, 8));
            rowmax[r] = x2;
        }
        float alpha[4];
        #pragma unroll
        for (int r = 0; r < 4; ++r) {
            float mnew = fmaxf(mr[r], rowmax[r]);
            alpha[r]   = exp2f(mr[r] - mnew);
            mr[r]      = mnew;
        }
        #pragma unroll
        for (int kc = 0; kc < 4; ++kc)
            #pragma unroll
            for (int r = 0; r < 4; ++r)
                s[kc][r] = exp2f(s[kc][r] - mr[r]);
        // rescale O and the fused-l accumulator (same recurrence)
        #pragma unroll
        for (int df = 0; df < 8; ++df)
            #pragma unroll
            for (int r = 0; r < 4; ++r) o[df][r] *= alpha[r];
        #pragma unroll
        for (int r = 0; r < 4; ++r) o8[r] *= alpha[r];

        __syncthreads();   // B3: all waves done reading Kl before Pl overwrite

        // ---- P -> Pl in pi-permuted layout: 4x ds_write_b64 ----
        #pragma unroll
        for (int r = 0; r < 4; ++r) {
            bf16x4 pk;
            #pragma unroll
            for (int kc = 0; kc < 4; ++kc) pk[kc] = (__bf16)s[kc][r];
            *(bf16x4*)&Pl[w][l4 * 4 + r][l15 * 4] = pk;
        }

        // ---- O += P V ; o8 += P * ones (df=8, fused l) ----
        __builtin_amdgcn_s_setprio(1);
        #pragma unroll
        for (int pc = 0; pc < 2; ++pc) {
            bf16x8 pa = *(const bf16x8*)&Pl[w][l15][pc * 32 + l4 * 8];
            #pragma unroll
            for (int df = 0; df < 8; ++df) {
                int cc  = df * 16 + l15;
                int kch = (pc * 4 + l4) ^ ((cc >> 3) & 7);
                bf16x8 vf = *(const bf16x8*)&Vt[cc][kch * 8];
                o[df] = __builtin_amdgcn_mfma_f32_16x16x32_bf16(pa, vf, o[df], 0, 0, 0);
            }
            {
                int kch = pc * 4 + l4;   // cc=128..143 -> xor term is 0
                bf16x8 vf = *(const bf16x8*)&Vt[128 + l15][kch * 8];
                o8 = __builtin_amdgcn_mfma_f32_16x16x32_bf16(pa, vf, o8, 0, 0, 0);
            }
        }
        __builtin_amdgcn_s_setprio(0);
    }

    if (!SPLIT || nch == 1) {
        // l for row l4*4+r lives in o8[r] at lanes with l15==0
        float inv[4];
        #pragma unroll
        for (int r = 0; r < 4; ++r)
            inv[r] = 1.0f / __shfl(o8[r], lane & 48);
        float* op = out + base;
        #pragma unroll
        for (int df = 0; df < 8; ++df)
            #pragma unroll
            for (int r = 0; r < 4; ++r) {
                int row = qb0 + w * 16 + l4 * 4 + r;
                op[(size_t)row * DIM + df * 16 + l15] = o[df][r] * inv[r];
            }
    } else {
        char* sp = part + (size_t)slot * SLOT_BYTES;
        float*  smp = (float*)sp;           // m[64] (log2 domain)
        float*  slp = (float*)(sp + 256);   // l[64]
        __bf16* sop = (__bf16*)(sp + 512);  // O[64][128] bf16
        #pragma unroll
        for (int r = 0; r < 4; ++r) {
            int rl = w * 16 + l4 * 4 + r;
            if (l15 == 0) { smp[rl] = mr[r]; slp[rl] = o8[r]; }
        }
        #pragma unroll
        for (int df = 0; df < 8; ++df)
            #pragma unroll
            for (int r = 0; r < 4; ++r) {
                int rl = w * 16 + l4 * 4 + r;
                sop[(size_t)rl * 128 + df * 16 + l15] = (__bf16)o[df][r];
            }
    }
}

// ---------------------------------------------------------------------------
// Kernel 3: combine partials for qt >= CHUNK. Grid (64-CHUNK, B), 256 thr.
// m is in log2 (exp2) domain -> weights use exp2f.
// ---------------------------------------------------------------------------
template <int CHUNK>
__global__ __launch_bounds__(256) void combine(
    const char* __restrict__ part, float* __restrict__ out)
{
    constexpr int TASKS = tasks_per_b(CHUNK);

    const int qt  = blockIdx.x + CHUNK;
    const int b   = blockIdx.y;
    const int g   = qt / CHUNK;
    const int nch = g + 1;
    const int slot0 = b * TASKS + CHUNK * g * (g + 1) / 2 + (qt % CHUNK) * nch;

    const int t   = threadIdx.x;
    const int row = t >> 2;
    const int c0  = (t & 3) * 32;

    float M = -INFINITY;
    for (int c = 0; c < nch; ++c) {
        const char* sp = part + (size_t)(slot0 + c) * SLOT_BYTES;
        M = fmaxf(M, ((const float*)sp)[row]);
    }
    float L = 0.f;
    for (int c = 0; c < nch; ++c) {
        const char* sp = part + (size_t)(slot0 + c) * SLOT_BYTES;
        L += ((const float*)(sp + 256))[row] * exp2f(((const float*)sp)[row] - M);
    }

    float acc[32];
    #pragma unroll
    for (int i = 0; i < 32; ++i) acc[i] = 0.f;
    for (int c = 0; c < nch; ++c) {
        const char* sp = part + (size_t)(slot0 + c) * SLOT_BYTES;
        float wgt = exp2f(((const float*)sp)[row] - M);
        const __bf16* op = (const __bf16*)(sp + 512) + (size_t)row * 128 + c0;
        #pragma unroll
        for (int i = 0; i < 4; ++i) {
            bf16x8 vv = *(const bf16x8*)(op + i * 8);
            #pragma unroll
            for (int j = 0; j < 8; ++j)
                acc[i * 8 + j] += wgt * (float)vv[j];
        }
    }
    float invL = 1.0f / L;
    float* o = out + ((size_t)b * SEQ + (size_t)qt * 64 + row) * DIM + c0;
    #pragma unroll
    for (int i = 0; i < 8; ++i) {
        float4 f;
        f.x = acc[i * 4 + 0] * invL; f.y = acc[i * 4 + 1] * invL;
        f.z = acc[i * 4 + 2] * invL; f.w = acc[i * 4 + 3] * invL;
        *(float4*)(o + i * 4) = f;
    }
}

// ---------------------------------------------------------------------------
extern "C" void kernel_launch(void* const* d_in, const int* in_sizes, int n_in,
                              void* d_out, int out_size, void* d_ws, size_t ws_size,
                              hipStream_t stream) {
    const float* x  = (const float*)d_in[0];
    const float* Wq = (const float*)d_in[1];
    const float* Wk = (const float*)d_in[2];
    const float* Wv = (const float*)d_in[3];
    float* out = (float*)d_out;

    __bf16* qw = (__bf16*)d_ws;
    __bf16* kw = qw + (size_t)BATCH * SEQ * DIM;
    __bf16* vw = kw + (size_t)BATCH * SEQ * DIM;
    char*   part = (char*)d_ws + QKV_BYTES;

    qkv_proj<<<dim3(BATCH * SEQ / 64, 3), 256, 0, stream>>>(x, Wq, Wk, Wv, qw, kw, vw);

    if (ws_size >= QKV_BYTES + part_bytes(4)) {
        attn<true, 4><<<dim3(tasks_per_b(4), BATCH), 256, 0, stream>>>(qw, kw, vw, out, part);
        combine<4><<<dim3(60, BATCH), 256, 0, stream>>>(part, out);
    } else if (ws_size >= QKV_BYTES + part_bytes(8)) {
        attn<true, 8><<<dim3(tasks_per_b(8), BATCH), 256, 0, stream>>>(qw, kw, vw, out, part);
        combine<8><<<dim3(56, BATCH), 256, 0, stream>>>(part, out);
    } else {
        attn<false, 8><<<dim3(SEQ / 64, BATCH), 256, 0, stream>>>(qw, kw, vw, out, part);
    }
}

// Round 14
// 94.336 us; speedup vs baseline: 1.3284x; 1.3284x over previous
//
#include <hip/hip_runtime.h>
#include <hip/hip_bf16.h>

// Problem constants
constexpr int BATCH = 4;
constexpr int SEQ   = 4096;
constexpr int DIM   = 128;   // head size

// Split-KV: KV tiles are 64 keys; CHUNK tiles per split block (templated).
constexpr size_t QKV_BYTES = (size_t)3 * BATCH * SEQ * DIM * 2;
// partial slot: m[64] f32, l[64] f32, O[64][128] bf16
constexpr size_t SLOT_BYTES = 64 * 4 + 64 * 4 + 64 * 128 * 2;   // 16896

constexpr int tasks_per_b(int chunk) {
    return chunk * (64 / chunk) * (64 / chunk + 1) / 2;
}
constexpr size_t part_bytes(int chunk) {
    return (size_t)BATCH * tasks_per_b(chunk) * SLOT_BYTES;
}

typedef __bf16 bf16x8 __attribute__((ext_vector_type(8)));
typedef __bf16 bf16x4 __attribute__((ext_vector_type(4)));
typedef float  f32x4  __attribute__((ext_vector_type(4)));

// ---------------------------------------------------------------------------
// Kernel 1: QKV projection, 64-row blocks. Grid (256, 3) = 768 blocks.
// ---------------------------------------------------------------------------
__global__ __launch_bounds__(256) void qkv_proj(
    const float* __restrict__ x,
    const float* __restrict__ Wq, const float* __restrict__ Wk,
    const float* __restrict__ Wv,
    __bf16* __restrict__ q, __bf16* __restrict__ k, __bf16* __restrict__ v)
{
    __shared__ __align__(16) __bf16 Xl[64][136];
    __shared__ __align__(16) __bf16 Wt[128][136];   // W transposed: Wt[d][c]

    const int t    = threadIdx.x;
    const int lane = t & 63;
    const int w    = t >> 6;
    const int l15  = lane & 15;
    const int l4   = lane >> 4;
    const int rowblk = blockIdx.x * 64;
    const int m      = blockIdx.y;

    const float* W  = (m == 0) ? Wq : (m == 1) ? Wk : Wv;
    __bf16*      op = (m == 0) ? q  : (m == 1) ? k  : v;

    #pragma unroll
    for (int i = 0; i < 8; ++i) {
        int idx = i * 256 + t;
        int r   = idx >> 5;
        int c4  = (idx & 31) << 2;
        float4 f = *(const float4*)(x + (size_t)(rowblk + r) * DIM + c4);
        __bf16* dst = &Xl[r][c4];
        dst[0] = (__bf16)f.x; dst[1] = (__bf16)f.y;
        dst[2] = (__bf16)f.z; dst[3] = (__bf16)f.w;
    }
    #pragma unroll
    for (int i = 0; i < 16; ++i) {
        int idx = i * 256 + t;
        int r   = idx >> 5;
        int c4  = (idx & 31) << 2;
        float4 f = *(const float4*)(W + (size_t)r * DIM + c4);
        Wt[c4 + 0][r] = (__bf16)f.x;
        Wt[c4 + 1][r] = (__bf16)f.y;
        Wt[c4 + 2][r] = (__bf16)f.z;
        Wt[c4 + 3][r] = (__bf16)f.w;
    }
    __syncthreads();

    f32x4 acc[8];
    #pragma unroll
    for (int cf = 0; cf < 8; ++cf) acc[cf] = (f32x4){0.f, 0.f, 0.f, 0.f};

    #pragma unroll
    for (int kc = 0; kc < 4; ++kc) {
        bf16x8 af = *(const bf16x8*)&Xl[w * 16 + l15][kc * 32 + l4 * 8];
        #pragma unroll
        for (int cf = 0; cf < 8; ++cf) {
            bf16x8 bfr = *(const bf16x8*)&Wt[cf * 16 + l15][kc * 32 + l4 * 8];
            acc[cf] = __builtin_amdgcn_mfma_f32_16x16x32_bf16(af, bfr, acc[cf], 0, 0, 0);
        }
    }

    #pragma unroll
    for (int cf = 0; cf < 8; ++cf)
        #pragma unroll
        for (int r2 = 0; r2 < 4; ++r2) {
            int row = rowblk + w * 16 + l4 * 4 + r2;
            int col = cf * 16 + l15;
            op[(size_t)row * DIM + col] = (__bf16)acc[cf][r2];
        }
}

// ---------------------------------------------------------------------------
// Kernel 2: causal flash attention, split-KV. R12's proven structure
// (pi-permuted P/V, aliased Pl<->Kl, 3 barriers, __expf, setprio) with two
// isolated additions, neither touching LDS size (35840 B -> 4 blocks/CU):
//  (a) in-register ones-column l-fusion: vones B-fragment (lane l15==0 holds
//      1.0, else 0) -> o8 = mfma(pa, vones, o8) accumulates row-sums; o8
//      receives the same alpha rescale as o, so it ends as l. Removes the
//      rowsum shuffle-reduce and lr bookkeeping. No LDS read, no LDS growth.
//  (b) V staging quad-packed: 8x ds_write_b64 (was 16x b32). New slots
//      4a..4a+3 = old keys {a,a+16,a+32,a+48}; swizzled cols contiguous and
//      8B-aligned; PV read path byte-identical.
// ---------------------------------------------------------------------------
template <bool SPLIT, int CHUNK>
__global__ __launch_bounds__(256) void attn(
    const __bf16* __restrict__ q, const __bf16* __restrict__ k,
    const __bf16* __restrict__ v, float* __restrict__ out,
    char* __restrict__ part)
{
    constexpr int NG    = 64 / CHUNK;
    constexpr int TASKS = tasks_per_b(CHUNK);

    __shared__ __align__(16) __bf16 KlBuf[64 * 136];   // Kl in QK^T phase; Pl in PV phase
    __shared__ __align__(16) __bf16 Vt[128][72];

    typedef __bf16 (*KlT)[136];
    typedef __bf16 (*PlT)[16][72];
    KlT Kl = (KlT)KlBuf;            // [64][136]
    PlT Pl = (PlT)KlBuf;            // [4][16][72] = 9216 B

    const int t    = threadIdx.x;
    const int lane = t & 63;
    const int w    = t >> 6;
    const int l15  = lane & 15;
    const int l4   = lane >> 4;
    const int b    = blockIdx.y;

    int qt, chunk, nch, slot = 0;
    if (SPLIT) {
        int j = blockIdx.x;                 // 0..TASKS-1
        int g = 0;
        while (g < NG - 1 && j >= CHUNK * (g + 1) * (g + 2) / 2) ++g;
        int r = j - CHUNK * g * (g + 1) / 2;
        nch   = g + 1;
        qt    = CHUNK * g + r / nch;
        chunk = r - (r / nch) * nch;
        slot  = b * TASKS + j;
    } else {
        qt = blockIdx.x; chunk = 0; nch = 1;
    }
    const int qb0 = qt * 64;
    const int jt0 = chunk * CHUNK;
    const int jtE = SPLIT ? min(jt0 + CHUNK, qt + 1) : qt + 1;
    const size_t base = (size_t)b * SEQ * DIM;

    // staging geometry
    const int rr  = t >> 4;            // 0..15  (K rows)
    const int c   = (t & 15) * 8;      // K d-base
    const int vq  = t >> 5;            // 0..7   (V quad base; quads vq, vq+8)
    const int vdq = (t & 31) * 4;      // V d-quad base

    // Q fragments (A-operand layout: row = l15, k = l4*8 + j + 32*dc)
    bf16x8 qf[4];
    {
        const __bf16* qrow = q + base + (size_t)(qb0 + w * 16 + l15) * DIM;
        #pragma unroll
        for (int dc = 0; dc < 4; ++dc)
            qf[dc] = *(const bf16x8*)(qrow + dc * 32 + l4 * 8);
    }

    // ones B-fragment: column 0 of the 16-col group = 1.0, others 0
    bf16x8 vones;
    {
        __bf16 one = (l15 == 0) ? (__bf16)1.0f : (__bf16)0.0f;
        #pragma unroll
        for (int j = 0; j < 8; ++j) vones[j] = one;
    }

    f32x4 o[8], o8;
    #pragma unroll
    for (int i = 0; i < 8; ++i) o[i] = (f32x4){0.f, 0.f, 0.f, 0.f};
    o8 = (f32x4){0.f, 0.f, 0.f, 0.f};
    float mr[4];
    #pragma unroll
    for (int r = 0; r < 4; ++r) mr[r] = -INFINITY;

    const float scale = 0.08838834764831845f;  // 1/sqrt(128)

    for (int jt = jt0; jt < jtE; ++jt) {
        __syncthreads();   // B1: all waves done with Pl(=KlBuf)/Vt of prev tile

        // ---- load K (linear, padded) and V (pi-permuted quad-packed) ----
        {
            const __bf16* kg = k + base + (size_t)jt * 64 * DIM;
            const __bf16* vg = v + base + (size_t)jt * 64 * DIM;
            #pragma unroll
            for (int i = 0; i < 4; ++i) {
                int row = i * 16 + rr;
                *(int4*)&Kl[row][c] = *(const int4*)(kg + (size_t)row * DIM + c);
            }
            #pragma unroll
            for (int h = 0; h < 2; ++h) {
                int a = h * 8 + vq;        // quad 0..15; new slots 4a..4a+3
                ushort4 r0 = *(const ushort4*)(vg + (size_t)(a     ) * DIM + vdq);
                ushort4 r1 = *(const ushort4*)(vg + (size_t)(a + 16) * DIM + vdq);
                ushort4 r2 = *(const ushort4*)(vg + (size_t)(a + 32) * DIM + vdq);
                ushort4 r3 = *(const ushort4*)(vg + (size_t)(a + 48) * DIM + vdq);
                #pragma unroll
                for (int e = 0; e < 4; ++e) {
                    int cc = vdq + e;                              // d index
                    int colBase = (((a >> 1) ^ ((cc >> 3) & 7)) << 3) | ((4 * a) & 7);
                    ushort4 pk;
                    pk.x = (&r0.x)[e]; pk.y = (&r1.x)[e];
                    pk.z = (&r2.x)[e]; pk.w = (&r3.x)[e];
                    *(ushort4*)&Vt[cc][colBase] = pk;
                }
            }
        }
        __syncthreads();   // B2: Kl/Vt visible

        // ---- S = Q K^T ----
        f32x4 s[4];
        __builtin_amdgcn_s_setprio(1);
        #pragma unroll
        for (int kc = 0; kc < 4; ++kc) {
            f32x4 acc = (f32x4){0.f, 0.f, 0.f, 0.f};
            #pragma unroll
            for (int dc = 0; dc < 4; ++dc) {
                bf16x8 kf = *(const bf16x8*)&Kl[kc * 16 + l15][dc * 32 + l4 * 8];
                acc = __builtin_amdgcn_mfma_f32_16x16x32_bf16(qf[dc], kf, acc, 0, 0, 0);
            }
            s[kc] = acc;
        }
        __builtin_amdgcn_s_setprio(0);

        // ---- scale + causal mask + online max ----
        const bool diag = (jt == qt);
        float rowmax[4];
        #pragma unroll
        for (int r = 0; r < 4; ++r) rowmax[r] = -INFINITY;
        #pragma unroll
        for (int kc = 0; kc < 4; ++kc) {
            int key = jt * 64 + kc * 16 + l15;
            #pragma unroll
            for (int r = 0; r < 4; ++r) {
                float sv = s[kc][r] * scale;
                if (diag) {
                    int qrow = qb0 + w * 16 + l4 * 4 + r;
                    if (key > qrow) sv = -INFINITY;
                }
                s[kc][r] = sv;
                rowmax[r] = fmaxf(rowmax[r], sv);
            }
        }
        #pragma unroll
        for (int r = 0; r < 4; ++r) {
            float x2 = rowmax[r];
            x2 = fmaxf(x2, __shfl_xor(x2, 1));
            x2 = fmaxf(x2, __shfl_xor(x2, 2));
            x2 = fmaxf(x2, __shfl_xor(x2, 4));
            x2 = fmaxf(x2, __shfl_xor(x2, 8));
            rowmax[r] = x2;
        }
        float alpha[4];
        #pragma unroll
        for (int r = 0; r < 4; ++r) {
            float mnew = fmaxf(mr[r], rowmax[r]);
            alpha[r]   = __expf(mr[r] - mnew);
            mr[r]      = mnew;
        }
        #pragma unroll
        for (int kc = 0; kc < 4; ++kc)
            #pragma unroll
            for (int r = 0; r < 4; ++r)
                s[kc][r] = __expf(s[kc][r] - mr[r]);
        // rescale O and the fused-l accumulator (same recurrence as lr)
        #pragma unroll
        for (int df = 0; df < 8; ++df)
            #pragma unroll
            for (int r = 0; r < 4; ++r) o[df][r] *= alpha[r];
        #pragma unroll
        for (int r = 0; r < 4; ++r) o8[r] *= alpha[r];

        __syncthreads();   // B3: all waves done reading Kl before Pl overwrite

        // ---- P -> Pl in pi-permuted layout: 4x ds_write_b64 ----
        #pragma unroll
        for (int r = 0; r < 4; ++r) {
            bf16x4 pk;
            #pragma unroll
            for (int kc = 0; kc < 4; ++kc) pk[kc] = (__bf16)s[kc][r];
            *(bf16x4*)&Pl[w][l4 * 4 + r][l15 * 4] = pk;
        }

        // ---- O += P V ; o8 += P * ones (register B-fragment, fused l) ----
        __builtin_amdgcn_s_setprio(1);
        #pragma unroll
        for (int pc = 0; pc < 2; ++pc) {
            bf16x8 pa = *(const bf16x8*)&Pl[w][l15][pc * 32 + l4 * 8];
            #pragma unroll
            for (int df = 0; df < 8; ++df) {
                int cc  = df * 16 + l15;
                int kch = (pc * 4 + l4) ^ ((cc >> 3) & 7);
                bf16x8 vf = *(const bf16x8*)&Vt[cc][kch * 8];
                o[df] = __builtin_amdgcn_mfma_f32_16x16x32_bf16(pa, vf, o[df], 0, 0, 0);
            }
            o8 = __builtin_amdgcn_mfma_f32_16x16x32_bf16(pa, vones, o8, 0, 0, 0);
        }
        __builtin_amdgcn_s_setprio(0);
    }

    if (!SPLIT || nch == 1) {
        // l for row l4*4+r lives in o8[r] at lanes with l15==0
        float inv[4];
        #pragma unroll
        for (int r = 0; r < 4; ++r)
            inv[r] = 1.0f / __shfl(o8[r], lane & 48);
        float* op = out + base;
        #pragma unroll
        for (int df = 0; df < 8; ++df)
            #pragma unroll
            for (int r = 0; r < 4; ++r) {
                int row = qb0 + w * 16 + l4 * 4 + r;
                op[(size_t)row * DIM + df * 16 + l15] = o[df][r] * inv[r];
            }
    } else {
        char* sp = part + (size_t)slot * SLOT_BYTES;
        float*  smp = (float*)sp;           // m[64]
        float*  slp = (float*)(sp + 256);   // l[64]
        __bf16* sop = (__bf16*)(sp + 512);  // O[64][128] bf16
        #pragma unroll
        for (int r = 0; r < 4; ++r) {
            int rl = w * 16 + l4 * 4 + r;
            if (l15 == 0) { smp[rl] = mr[r]; slp[rl] = o8[r]; }
        }
        #pragma unroll
        for (int df = 0; df < 8; ++df)
            #pragma unroll
            for (int r = 0; r < 4; ++r) {
                int rl = w * 16 + l4 * 4 + r;
                sop[(size_t)rl * 128 + df * 16 + l15] = (__bf16)o[df][r];
            }
    }
}

// ---------------------------------------------------------------------------
// Kernel 3: combine partials for qt >= CHUNK. Grid (64-CHUNK, B), 256 thr.
// ---------------------------------------------------------------------------
template <int CHUNK>
__global__ __launch_bounds__(256) void combine(
    const char* __restrict__ part, float* __restrict__ out)
{
    constexpr int TASKS = tasks_per_b(CHUNK);

    const int qt  = blockIdx.x + CHUNK;
    const int b   = blockIdx.y;
    const int g   = qt / CHUNK;
    const int nch = g + 1;
    const int slot0 = b * TASKS + CHUNK * g * (g + 1) / 2 + (qt % CHUNK) * nch;

    const int t   = threadIdx.x;
    const int row = t >> 2;
    const int c0  = (t & 3) * 32;

    float M = -INFINITY;
    for (int c = 0; c < nch; ++c) {
        const char* sp = part + (size_t)(slot0 + c) * SLOT_BYTES;
        M = fmaxf(M, ((const float*)sp)[row]);
    }
    float L = 0.f;
    for (int c = 0; c < nch; ++c) {
        const char* sp = part + (size_t)(slot0 + c) * SLOT_BYTES;
        L += ((const float*)(sp + 256))[row] * __expf(((const float*)sp)[row] - M);
    }

    float acc[32];
    #pragma unroll
    for (int i = 0; i < 32; ++i) acc[i] = 0.f;
    for (int c = 0; c < nch; ++c) {
        const char* sp = part + (size_t)(slot0 + c) * SLOT_BYTES;
        float wgt = __expf(((const float*)sp)[row] - M);
        const __bf16* op = (const __bf16*)(sp + 512) + (size_t)row * 128 + c0;
        #pragma unroll
        for (int i = 0; i < 4; ++i) {
            bf16x8 vv = *(const bf16x8*)(op + i * 8);
            #pragma unroll
            for (int j = 0; j < 8; ++j)
                acc[i * 8 + j] += wgt * (float)vv[j];
        }
    }
    float invL = 1.0f / L;
    float* o = out + ((size_t)b * SEQ + (size_t)qt * 64 + row) * DIM + c0;
    #pragma unroll
    for (int i = 0; i < 8; ++i) {
        float4 f;
        f.x = acc[i * 4 + 0] * invL; f.y = acc[i * 4 + 1] * invL;
        f.z = acc[i * 4 + 2] * invL; f.w = acc[i * 4 + 3] * invL;
        *(float4*)(o + i * 4) = f;
    }
}

// ---------------------------------------------------------------------------
extern "C" void kernel_launch(void* const* d_in, const int* in_sizes, int n_in,
                              void* d_out, int out_size, void* d_ws, size_t ws_size,
                              hipStream_t stream) {
    const float* x  = (const float*)d_in[0];
    const float* Wq = (const float*)d_in[1];
    const float* Wk = (const float*)d_in[2];
    const float* Wv = (const float*)d_in[3];
    float* out = (float*)d_out;

    __bf16* qw = (__bf16*)d_ws;
    __bf16* kw = qw + (size_t)BATCH * SEQ * DIM;
    __bf16* vw = kw + (size_t)BATCH * SEQ * DIM;
    char*   part = (char*)d_ws + QKV_BYTES;

    qkv_proj<<<dim3(BATCH * SEQ / 64, 3), 256, 0, stream>>>(x, Wq, Wk, Wv, qw, kw, vw);

    if (ws_size >= QKV_BYTES + part_bytes(4)) {
        attn<true, 4><<<dim3(tasks_per_b(4), BATCH), 256, 0, stream>>>(qw, kw, vw, out, part);
        combine<4><<<dim3(60, BATCH), 256, 0, stream>>>(part, out);
    } else if (ws_size >= QKV_BYTES + part_bytes(8)) {
        attn<true, 8><<<dim3(tasks_per_b(8), BATCH), 256, 0, stream>>>(qw, kw, vw, out, part);
        combine<8><<<dim3(56, BATCH), 256, 0, stream>>>(part, out);
    } else {
        attn<false, 8><<<dim3(SEQ / 64, BATCH), 256, 0, stream>>>(qw, kw, vw, out, part);
    }
}

// Round 15
// 89.399 us; speedup vs baseline: 1.4018x; 1.0552x over previous
//
#include <hip/hip_runtime.h>
#include <hip/hip_bf16.h>

// Problem constants
constexpr int BATCH = 4;
constexpr int SEQ   = 4096;
constexpr int DIM   = 128;   // head size

// Split-KV: KV tiles are 64 keys; CHUNK tiles per split block (templated).
constexpr size_t QKV_BYTES = (size_t)3 * BATCH * SEQ * DIM * 2;
// partial slot: m[64] f32, l[64] f32, O[64][128] bf16
constexpr size_t SLOT_BYTES = 64 * 4 + 64 * 4 + 64 * 128 * 2;   // 16896

constexpr int tasks_per_b(int chunk) {
    return chunk * (64 / chunk) * (64 / chunk + 1) / 2;
}
constexpr size_t part_bytes(int chunk) {
    return (size_t)BATCH * tasks_per_b(chunk) * SLOT_BYTES;
}

typedef __bf16 bf16x8 __attribute__((ext_vector_type(8)));
typedef __bf16 bf16x4 __attribute__((ext_vector_type(4)));
typedef float  f32x4  __attribute__((ext_vector_type(4)));

// ---------------------------------------------------------------------------
// Kernel 1: QKV projection, 64-row blocks. Grid (256, 3) = 768 blocks.
// ---------------------------------------------------------------------------
__global__ __launch_bounds__(256) void qkv_proj(
    const float* __restrict__ x,
    const float* __restrict__ Wq, const float* __restrict__ Wk,
    const float* __restrict__ Wv,
    __bf16* __restrict__ q, __bf16* __restrict__ k, __bf16* __restrict__ v)
{
    __shared__ __align__(16) __bf16 Xl[64][136];
    __shared__ __align__(16) __bf16 Wt[128][136];   // W transposed: Wt[d][c]

    const int t    = threadIdx.x;
    const int lane = t & 63;
    const int w    = t >> 6;
    const int l15  = lane & 15;
    const int l4   = lane >> 4;
    const int rowblk = blockIdx.x * 64;
    const int m      = blockIdx.y;

    const float* W  = (m == 0) ? Wq : (m == 1) ? Wk : Wv;
    __bf16*      op = (m == 0) ? q  : (m == 1) ? k  : v;

    #pragma unroll
    for (int i = 0; i < 8; ++i) {
        int idx = i * 256 + t;
        int r   = idx >> 5;
        int c4  = (idx & 31) << 2;
        float4 f = *(const float4*)(x + (size_t)(rowblk + r) * DIM + c4);
        __bf16* dst = &Xl[r][c4];
        dst[0] = (__bf16)f.x; dst[1] = (__bf16)f.y;
        dst[2] = (__bf16)f.z; dst[3] = (__bf16)f.w;
    }
    #pragma unroll
    for (int i = 0; i < 16; ++i) {
        int idx = i * 256 + t;
        int r   = idx >> 5;
        int c4  = (idx & 31) << 2;
        float4 f = *(const float4*)(W + (size_t)r * DIM + c4);
        Wt[c4 + 0][r] = (__bf16)f.x;
        Wt[c4 + 1][r] = (__bf16)f.y;
        Wt[c4 + 2][r] = (__bf16)f.z;
        Wt[c4 + 3][r] = (__bf16)f.w;
    }
    __syncthreads();

    f32x4 acc[8];
    #pragma unroll
    for (int cf = 0; cf < 8; ++cf) acc[cf] = (f32x4){0.f, 0.f, 0.f, 0.f};

    #pragma unroll
    for (int kc = 0; kc < 4; ++kc) {
        bf16x8 af = *(const bf16x8*)&Xl[w * 16 + l15][kc * 32 + l4 * 8];
        #pragma unroll
        for (int cf = 0; cf < 8; ++cf) {
            bf16x8 bfr = *(const bf16x8*)&Wt[cf * 16 + l15][kc * 32 + l4 * 8];
            acc[cf] = __builtin_amdgcn_mfma_f32_16x16x32_bf16(af, bfr, acc[cf], 0, 0, 0);
        }
    }

    #pragma unroll
    for (int cf = 0; cf < 8; ++cf)
        #pragma unroll
        for (int r2 = 0; r2 < 4; ++r2) {
            int row = rowblk + w * 16 + l4 * 4 + r2;
            int col = cf * 16 + l15;
            op[(size_t)row * DIM + col] = (__bf16)acc[cf][r2];
        }
}

// ---------------------------------------------------------------------------
// Kernel 2: causal flash attention, split-KV. EXACT R12 kernel (best verified:
// attn 59.5us): pi-permuted P/V, aliased Pl<->Kl + 3 barriers, 16x b32 V
// staging, __expf softmax, setprio around MFMA clusters, bf16 O-partials.
// ---------------------------------------------------------------------------
template <bool SPLIT, int CHUNK>
__global__ __launch_bounds__(256) void attn(
    const __bf16* __restrict__ q, const __bf16* __restrict__ k,
    const __bf16* __restrict__ v, float* __restrict__ out,
    char* __restrict__ part)
{
    constexpr int NG    = 64 / CHUNK;
    constexpr int TASKS = tasks_per_b(CHUNK);

    __shared__ __align__(16) __bf16 KlBuf[64 * 136];   // Kl in QK^T phase; Pl in PV phase
    __shared__ __align__(16) __bf16 Vt[128][72];

    typedef __bf16 (*KlT)[136];
    typedef __bf16 (*PlT)[16][72];
    KlT Kl = (KlT)KlBuf;            // [64][136]
    PlT Pl = (PlT)KlBuf;            // [4][16][72] = 9216 B

    const int t    = threadIdx.x;
    const int lane = t & 63;
    const int w    = t >> 6;
    const int l15  = lane & 15;
    const int l4   = lane >> 4;
    const int b    = blockIdx.y;

    int qt, chunk, nch, slot = 0;
    if (SPLIT) {
        int j = blockIdx.x;                 // 0..TASKS-1
        int g = 0;
        while (g < NG - 1 && j >= CHUNK * (g + 1) * (g + 2) / 2) ++g;
        int r = j - CHUNK * g * (g + 1) / 2;
        nch   = g + 1;
        qt    = CHUNK * g + r / nch;
        chunk = r - (r / nch) * nch;
        slot  = b * TASKS + j;
    } else {
        qt = blockIdx.x; chunk = 0; nch = 1;
    }
    const int qb0 = qt * 64;
    const int jt0 = chunk * CHUNK;
    const int jtE = SPLIT ? min(jt0 + CHUNK, qt + 1) : qt + 1;
    const size_t base = (size_t)b * SEQ * DIM;

    // staging geometry
    const int rr = t >> 4;             // 0..15  (K rows)
    const int c  = (t & 15) * 8;       // K d-base
    const int vp = t >> 5;             // 0..7   (V pair id within group)
    const int vd = (t & 31) * 4;       // V d-base

    // Q fragments (A-operand layout: row = l15, k = l4*8 + j + 32*dc)
    bf16x8 qf[4];
    {
        const __bf16* qrow = q + base + (size_t)(qb0 + w * 16 + l15) * DIM;
        #pragma unroll
        for (int dc = 0; dc < 4; ++dc)
            qf[dc] = *(const bf16x8*)(qrow + dc * 32 + l4 * 8);
    }

    f32x4 o[8];
    #pragma unroll
    for (int i = 0; i < 8; ++i) o[i] = (f32x4){0.f, 0.f, 0.f, 0.f};
    float mr[4], lr[4];
    #pragma unroll
    for (int r = 0; r < 4; ++r) { mr[r] = -INFINITY; lr[r] = 0.f; }

    const float scale = 0.08838834764831845f;  // 1/sqrt(128)

    for (int jt = jt0; jt < jtE; ++jt) {
        __syncthreads();   // B1: all waves done with Pl(=KlBuf)/Vt of prev tile

        // ---- load K (linear, padded) and V (pi-permuted pair-packed) ----
        {
            const __bf16* kg = k + base + (size_t)jt * 64 * DIM;
            const __bf16* vg = v + base + (size_t)jt * 64 * DIM;
            #pragma unroll
            for (int i = 0; i < 4; ++i) {
                int row = i * 16 + rr;
                *(int4*)&Kl[row][c] = *(const int4*)(kg + (size_t)row * DIM + c);
                // V: pair (ka, ka+16) -> adjacent new indices (kn, kn+1)
                int p    = i * 8 + vp;        // pair id 0..31
                int l15_ = p >> 1;
                int kcp  = p & 1;
                int ka   = 32 * kcp + l15_;   // old key (even new slot)
                int kn   = 4 * l15_ + 2 * kcp;// permuted index, even
                ushort4 va = *(const ushort4*)(vg + (size_t)ka * DIM + vd);
                ushort4 vb = *(const ushort4*)(vg + (size_t)(ka + 16) * DIM + vd);
                #pragma unroll
                for (int e = 0; e < 4; ++e) {
                    int cc  = vd + e;                                  // d index
                    int col = (((kn >> 3) ^ ((cc >> 3) & 7)) << 3) | (kn & 7);
                    ushort2 pr;
                    pr.x = (&va.x)[e];
                    pr.y = (&vb.x)[e];
                    *(ushort2*)&Vt[cc][col] = pr;
                }
            }
        }
        __syncthreads();   // B2: Kl/Vt visible

        // ---- S = Q K^T ----
        f32x4 s[4];
        __builtin_amdgcn_s_setprio(1);
        #pragma unroll
        for (int kc = 0; kc < 4; ++kc) {
            f32x4 acc = (f32x4){0.f, 0.f, 0.f, 0.f};
            #pragma unroll
            for (int dc = 0; dc < 4; ++dc) {
                bf16x8 kf = *(const bf16x8*)&Kl[kc * 16 + l15][dc * 32 + l4 * 8];
                acc = __builtin_amdgcn_mfma_f32_16x16x32_bf16(qf[dc], kf, acc, 0, 0, 0);
            }
            s[kc] = acc;
        }
        __builtin_amdgcn_s_setprio(0);

        // ---- scale + causal mask + online softmax ----
        const bool diag = (jt == qt);
        float rowmax[4];
        #pragma unroll
        for (int r = 0; r < 4; ++r) rowmax[r] = -INFINITY;
        #pragma unroll
        for (int kc = 0; kc < 4; ++kc) {
            int key = jt * 64 + kc * 16 + l15;
            #pragma unroll
            for (int r = 0; r < 4; ++r) {
                float sv = s[kc][r] * scale;
                if (diag) {
                    int qrow = qb0 + w * 16 + l4 * 4 + r;
                    if (key > qrow) sv = -INFINITY;
                }
                s[kc][r] = sv;
                rowmax[r] = fmaxf(rowmax[r], sv);
            }
        }
        #pragma unroll
        for (int r = 0; r < 4; ++r) {
            float x2 = rowmax[r];
            x2 = fmaxf(x2, __shfl_xor(x2, 1));
            x2 = fmaxf(x2, __shfl_xor(x2, 2));
            x2 = fmaxf(x2, __shfl_xor(x2, 4));
            x2 = fmaxf(x2, __shfl_xor(x2, 8));
            rowmax[r] = x2;
        }
        float alpha[4];
        #pragma unroll
        for (int r = 0; r < 4; ++r) {
            float mnew = fmaxf(mr[r], rowmax[r]);
            alpha[r]   = __expf(mr[r] - mnew);
            mr[r]      = mnew;
        }
        float rowsum[4] = {0.f, 0.f, 0.f, 0.f};
        #pragma unroll
        for (int kc = 0; kc < 4; ++kc)
            #pragma unroll
            for (int r = 0; r < 4; ++r) {
                float p = __expf(s[kc][r] - mr[r]);
                s[kc][r] = p;
                rowsum[r] += p;
            }
        #pragma unroll
        for (int r = 0; r < 4; ++r) {
            float x2 = rowsum[r];
            x2 += __shfl_xor(x2, 1);
            x2 += __shfl_xor(x2, 2);
            x2 += __shfl_xor(x2, 4);
            x2 += __shfl_xor(x2, 8);
            lr[r] = lr[r] * alpha[r] + x2;
        }
        #pragma unroll
        for (int df = 0; df < 8; ++df)
            #pragma unroll
            for (int r = 0; r < 4; ++r) o[df][r] *= alpha[r];

        __syncthreads();   // B3: all waves done reading Kl before Pl overwrite

        // ---- P -> Pl in pi-permuted layout: 4x ds_write_b64 ----
        #pragma unroll
        for (int r = 0; r < 4; ++r) {
            bf16x4 pk;
            #pragma unroll
            for (int kc = 0; kc < 4; ++kc) pk[kc] = (__bf16)s[kc][r];
            *(bf16x4*)&Pl[w][l4 * 4 + r][l15 * 4] = pk;
        }

        // ---- O += P V (both operands enumerate pi(k)) ----
        __builtin_amdgcn_s_setprio(1);
        #pragma unroll
        for (int pc = 0; pc < 2; ++pc) {
            bf16x8 pa = *(const bf16x8*)&Pl[w][l15][pc * 32 + l4 * 8];
            #pragma unroll
            for (int df = 0; df < 8; ++df) {
                int cc  = df * 16 + l15;
                int kch = (pc * 4 + l4) ^ ((cc >> 3) & 7);
                bf16x8 vf = *(const bf16x8*)&Vt[cc][kch * 8];
                o[df] = __builtin_amdgcn_mfma_f32_16x16x32_bf16(pa, vf, o[df], 0, 0, 0);
            }
        }
        __builtin_amdgcn_s_setprio(0);
    }

    if (!SPLIT || nch == 1) {
        float inv[4];
        #pragma unroll
        for (int r = 0; r < 4; ++r) inv[r] = 1.0f / lr[r];
        float* op = out + base;
        #pragma unroll
        for (int df = 0; df < 8; ++df)
            #pragma unroll
            for (int r = 0; r < 4; ++r) {
                int row = qb0 + w * 16 + l4 * 4 + r;
                op[(size_t)row * DIM + df * 16 + l15] = o[df][r] * inv[r];
            }
    } else {
        char* sp = part + (size_t)slot * SLOT_BYTES;
        float*  smp = (float*)sp;           // m[64]
        float*  slp = (float*)(sp + 256);   // l[64]
        __bf16* sop = (__bf16*)(sp + 512);  // O[64][128] bf16
        #pragma unroll
        for (int r = 0; r < 4; ++r) {
            int rl = w * 16 + l4 * 4 + r;
            if (l15 == 0) { smp[rl] = mr[r]; slp[rl] = lr[r]; }
        }
        #pragma unroll
        for (int df = 0; df < 8; ++df)
            #pragma unroll
            for (int r = 0; r < 4; ++r) {
                int rl = w * 16 + l4 * 4 + r;
                sop[(size_t)rl * 128 + df * 16 + l15] = (__bf16)o[df][r];
            }
    }
}

// ---------------------------------------------------------------------------
// Kernel 3: combine partials for qt >= CHUNK. 4x parallelism vs before:
// grid ((64-CHUNK)*4, B); each block does a 16-row quarter of one qt.
// Thread t: row = quarter*16 + (t>>4), cols [(t&15)*8, +8) (16B bf16 loads,
// 256B contiguous per 16 threads). Work/traffic/numerics identical.
// ---------------------------------------------------------------------------
template <int CHUNK>
__global__ __launch_bounds__(256) void combine(
    const char* __restrict__ part, float* __restrict__ out)
{
    constexpr int TASKS = tasks_per_b(CHUNK);

    const int qt  = (blockIdx.x >> 2) + CHUNK;
    const int qr  = blockIdx.x & 3;          // row quarter
    const int b   = blockIdx.y;
    const int g   = qt / CHUNK;
    const int nch = g + 1;
    const int slot0 = b * TASKS + CHUNK * g * (g + 1) / 2 + (qt % CHUNK) * nch;

    const int t   = threadIdx.x;
    const int row = qr * 16 + (t >> 4);      // 0..63
    const int c0  = (t & 15) * 8;            // 8-col strip

    float M = -INFINITY;
    for (int c = 0; c < nch; ++c) {
        const char* sp = part + (size_t)(slot0 + c) * SLOT_BYTES;
        M = fmaxf(M, ((const float*)sp)[row]);
    }
    float L = 0.f;
    for (int c = 0; c < nch; ++c) {
        const char* sp = part + (size_t)(slot0 + c) * SLOT_BYTES;
        L += ((const float*)(sp + 256))[row] * __expf(((const float*)sp)[row] - M);
    }

    float acc[8];
    #pragma unroll
    for (int i = 0; i < 8; ++i) acc[i] = 0.f;
    for (int c = 0; c < nch; ++c) {
        const char* sp = part + (size_t)(slot0 + c) * SLOT_BYTES;
        float wgt = __expf(((const float*)sp)[row] - M);
        const __bf16* op = (const __bf16*)(sp + 512) + (size_t)row * 128 + c0;
        bf16x8 vv = *(const bf16x8*)op;
        #pragma unroll
        for (int j = 0; j < 8; ++j)
            acc[j] += wgt * (float)vv[j];
    }
    float invL = 1.0f / L;
    float* o = out + ((size_t)b * SEQ + (size_t)qt * 64 + row) * DIM + c0;
    float4 f0, f1;
    f0.x = acc[0] * invL; f0.y = acc[1] * invL;
    f0.z = acc[2] * invL; f0.w = acc[3] * invL;
    f1.x = acc[4] * invL; f1.y = acc[5] * invL;
    f1.z = acc[6] * invL; f1.w = acc[7] * invL;
    *(float4*)o = f0;
    *(float4*)(o + 4) = f1;
}

// ---------------------------------------------------------------------------
extern "C" void kernel_launch(void* const* d_in, const int* in_sizes, int n_in,
                              void* d_out, int out_size, void* d_ws, size_t ws_size,
                              hipStream_t stream) {
    const float* x  = (const float*)d_in[0];
    const float* Wq = (const float*)d_in[1];
    const float* Wk = (const float*)d_in[2];
    const float* Wv = (const float*)d_in[3];
    float* out = (float*)d_out;

    __bf16* qw = (__bf16*)d_ws;
    __bf16* kw = qw + (size_t)BATCH * SEQ * DIM;
    __bf16* vw = kw + (size_t)BATCH * SEQ * DIM;
    char*   part = (char*)d_ws + QKV_BYTES;

    qkv_proj<<<dim3(BATCH * SEQ / 64, 3), 256, 0, stream>>>(x, Wq, Wk, Wv, qw, kw, vw);

    if (ws_size >= QKV_BYTES + part_bytes(4)) {
        attn<true, 4><<<dim3(tasks_per_b(4), BATCH), 256, 0, stream>>>(qw, kw, vw, out, part);
        combine<4><<<dim3(60 * 4, BATCH), 256, 0, stream>>>(part, out);
    } else if (ws_size >= QKV_BYTES + part_bytes(8)) {
        attn<true, 8><<<dim3(tasks_per_b(8), BATCH), 256, 0, stream>>>(qw, kw, vw, out, part);
        combine<8><<<dim3(56 * 4, BATCH), 256, 0, stream>>>(part, out);
    } else {
        attn<false, 8><<<dim3(SEQ / 64, BATCH), 256, 0, stream>>>(qw, kw, vw, out, part);
    }
}

// Round 16
// 82.546 us; speedup vs baseline: 1.5181x; 1.0830x over previous
//
#include <hip/hip_runtime.h>
#include <hip/hip_bf16.h>

// Problem constants
constexpr int BATCH = 4;
constexpr int SEQ   = 4096;
constexpr int DIM   = 128;   // head size

// Split-KV: KV tiles are 64 keys; CHUNK tiles per split block (templated).
constexpr size_t QKV_BYTES = (size_t)3 * BATCH * SEQ * DIM * 2;
// partial slot: m[64] f32, l[64] f32, O[64][128] bf16
constexpr size_t SLOT_BYTES = 64 * 4 + 64 * 4 + 64 * 128 * 2;   // 16896

constexpr int tasks_per_b(int chunk) {
    return chunk * (64 / chunk) * (64 / chunk + 1) / 2;
}
constexpr size_t part_bytes(int chunk) {
    return (size_t)BATCH * tasks_per_b(chunk) * SLOT_BYTES;
}

typedef __bf16 bf16x8 __attribute__((ext_vector_type(8)));
typedef __bf16 bf16x4 __attribute__((ext_vector_type(4)));
typedef float  f32x4  __attribute__((ext_vector_type(4)));

// ---------------------------------------------------------------------------
// Kernel 1: QKV projection, 64-row blocks. Grid (256, 3) = 768 blocks.
// R16 changes (this kernel only):
//  (a) Wt transpose-write XOR swizzle c' = c ^ 8*((d>>2)&7): spreads the
//      previously ~16-way-conflicted scalar writes to ~4-way; reads apply
//      the same 8-aligned XOR so ds_read_b128 stays contiguous/aligned.
//  (b) Epilogue: stage O into Xl (dead after MFMA) with a row-XOR swizzle,
//      then 4x ds_read_b128 + 4x global_store_dwordx4 per thread (64B
//      contiguous per 4 lanes) instead of 32 scalar bf16 stores.
// ---------------------------------------------------------------------------
__global__ __launch_bounds__(256) void qkv_proj(
    const float* __restrict__ x,
    const float* __restrict__ Wq, const float* __restrict__ Wk,
    const float* __restrict__ Wv,
    __bf16* __restrict__ q, __bf16* __restrict__ k, __bf16* __restrict__ v)
{
    __shared__ __align__(16) __bf16 Xl[64][136];    // X tile; then O staging
    __shared__ __align__(16) __bf16 Wt[128][136];   // W transposed: Wt[d][c^swz(d)]

    const int t    = threadIdx.x;
    const int lane = t & 63;
    const int w    = t >> 6;
    const int l15  = lane & 15;
    const int l4   = lane >> 4;
    const int rowblk = blockIdx.x * 64;
    const int m      = blockIdx.y;

    const float* W  = (m == 0) ? Wq : (m == 1) ? Wk : Wv;
    __bf16*      op = (m == 0) ? q  : (m == 1) ? k  : v;

    // X tile (64x128 f32) -> bf16 LDS
    #pragma unroll
    for (int i = 0; i < 8; ++i) {
        int idx = i * 256 + t;
        int r   = idx >> 5;
        int c4  = (idx & 31) << 2;
        float4 f = *(const float4*)(x + (size_t)(rowblk + r) * DIM + c4);
        __bf16* dst = &Xl[r][c4];
        dst[0] = (__bf16)f.x; dst[1] = (__bf16)f.y;
        dst[2] = (__bf16)f.z; dst[3] = (__bf16)f.w;
    }
    // W (row-major [c][d]) transposed into Wt[d][c ^ swz(d)]
    #pragma unroll
    for (int i = 0; i < 16; ++i) {
        int idx = i * 256 + t;
        int r   = idx >> 5;          // c index
        int c4  = (idx & 31) << 2;   // d base
        float4 f = *(const float4*)(W + (size_t)r * DIM + c4);
        #pragma unroll
        for (int e = 0; e < 4; ++e) {
            int d  = c4 + e;
            int cs = r ^ (8 * ((d >> 2) & 7));
            Wt[d][cs] = (e == 0) ? (__bf16)f.x : (e == 1) ? (__bf16)f.y
                       : (e == 2) ? (__bf16)f.z : (__bf16)f.w;
        }
    }
    __syncthreads();

    f32x4 acc[8];
    #pragma unroll
    for (int cf = 0; cf < 8; ++cf) acc[cf] = (f32x4){0.f, 0.f, 0.f, 0.f};

    #pragma unroll
    for (int kc = 0; kc < 4; ++kc) {
        bf16x8 af = *(const bf16x8*)&Xl[w * 16 + l15][kc * 32 + l4 * 8];
        #pragma unroll
        for (int cf = 0; cf < 8; ++cf) {
            int d   = cf * 16 + l15;
            int cb  = (kc * 32 + l4 * 8) ^ (8 * ((d >> 2) & 7));
            bf16x8 bfr = *(const bf16x8*)&Wt[d][cb];
            acc[cf] = __builtin_amdgcn_mfma_f32_16x16x32_bf16(af, bfr, acc[cf], 0, 0, 0);
        }
    }

    __syncthreads();   // all waves done reading Xl/Wt

    // stage O into Xl (row-XOR swizzle: col' = col ^ 8*((row>>2)&3))
    #pragma unroll
    for (int cf = 0; cf < 8; ++cf)
        #pragma unroll
        for (int r2 = 0; r2 < 4; ++r2) {
            int rowl = w * 16 + l4 * 4 + r2;
            int col  = cf * 16 + l15;
            Xl[rowl][col ^ (8 * ((rowl >> 2) & 3))] = (__bf16)acc[cf][r2];
        }
    __syncthreads();

    // coalesced stores: thread t -> row t>>2, 4x 16B chunks
    {
        int rowl = t >> 2;
        int sw   = 8 * ((rowl >> 2) & 3);
        __bf16* orow = op + (size_t)(rowblk + rowl) * DIM;
        #pragma unroll
        for (int u = 0; u < 4; ++u) {
            int col8 = u * 32 + (t & 3) * 8;
            bf16x8 vv = *(const bf16x8*)&Xl[rowl][col8 ^ sw];
            *(bf16x8*)(orow + col8) = vv;
        }
    }
}

// ---------------------------------------------------------------------------
// Kernel 2: causal flash attention, split-KV. EXACT R12/R15 kernel (best
// verified: attn 59.5us): pi-permuted P/V, aliased Pl<->Kl + 3 barriers,
// 16x b32 V staging, __expf softmax, setprio, bf16 O-partials.
// ---------------------------------------------------------------------------
template <bool SPLIT, int CHUNK>
__global__ __launch_bounds__(256) void attn(
    const __bf16* __restrict__ q, const __bf16* __restrict__ k,
    const __bf16* __restrict__ v, float* __restrict__ out,
    char* __restrict__ part)
{
    constexpr int NG    = 64 / CHUNK;
    constexpr int TASKS = tasks_per_b(CHUNK);

    __shared__ __align__(16) __bf16 KlBuf[64 * 136];   // Kl in QK^T phase; Pl in PV phase
    __shared__ __align__(16) __bf16 Vt[128][72];

    typedef __bf16 (*KlT)[136];
    typedef __bf16 (*PlT)[16][72];
    KlT Kl = (KlT)KlBuf;            // [64][136]
    PlT Pl = (PlT)KlBuf;            // [4][16][72] = 9216 B

    const int t    = threadIdx.x;
    const int lane = t & 63;
    const int w    = t >> 6;
    const int l15  = lane & 15;
    const int l4   = lane >> 4;
    const int b    = blockIdx.y;

    int qt, chunk, nch, slot = 0;
    if (SPLIT) {
        int j = blockIdx.x;                 // 0..TASKS-1
        int g = 0;
        while (g < NG - 1 && j >= CHUNK * (g + 1) * (g + 2) / 2) ++g;
        int r = j - CHUNK * g * (g + 1) / 2;
        nch   = g + 1;
        qt    = CHUNK * g + r / nch;
        chunk = r - (r / nch) * nch;
        slot  = b * TASKS + j;
    } else {
        qt = blockIdx.x; chunk = 0; nch = 1;
    }
    const int qb0 = qt * 64;
    const int jt0 = chunk * CHUNK;
    const int jtE = SPLIT ? min(jt0 + CHUNK, qt + 1) : qt + 1;
    const size_t base = (size_t)b * SEQ * DIM;

    // staging geometry
    const int rr = t >> 4;             // 0..15  (K rows)
    const int c  = (t & 15) * 8;       // K d-base
    const int vp = t >> 5;             // 0..7   (V pair id within group)
    const int vd = (t & 31) * 4;       // V d-base

    // Q fragments (A-operand layout: row = l15, k = l4*8 + j + 32*dc)
    bf16x8 qf[4];
    {
        const __bf16* qrow = q + base + (size_t)(qb0 + w * 16 + l15) * DIM;
        #pragma unroll
        for (int dc = 0; dc < 4; ++dc)
            qf[dc] = *(const bf16x8*)(qrow + dc * 32 + l4 * 8);
    }

    f32x4 o[8];
    #pragma unroll
    for (int i = 0; i < 8; ++i) o[i] = (f32x4){0.f, 0.f, 0.f, 0.f};
    float mr[4], lr[4];
    #pragma unroll
    for (int r = 0; r < 4; ++r) { mr[r] = -INFINITY; lr[r] = 0.f; }

    const float scale = 0.08838834764831845f;  // 1/sqrt(128)

    for (int jt = jt0; jt < jtE; ++jt) {
        __syncthreads();   // B1: all waves done with Pl(=KlBuf)/Vt of prev tile

        // ---- load K (linear, padded) and V (pi-permuted pair-packed) ----
        {
            const __bf16* kg = k + base + (size_t)jt * 64 * DIM;
            const __bf16* vg = v + base + (size_t)jt * 64 * DIM;
            #pragma unroll
            for (int i = 0; i < 4; ++i) {
                int row = i * 16 + rr;
                *(int4*)&Kl[row][c] = *(const int4*)(kg + (size_t)row * DIM + c);
                // V: pair (ka, ka+16) -> adjacent new indices (kn, kn+1)
                int p    = i * 8 + vp;        // pair id 0..31
                int l15_ = p >> 1;
                int kcp  = p & 1;
                int ka   = 32 * kcp + l15_;   // old key (even new slot)
                int kn   = 4 * l15_ + 2 * kcp;// permuted index, even
                ushort4 va = *(const ushort4*)(vg + (size_t)ka * DIM + vd);
                ushort4 vb = *(const ushort4*)(vg + (size_t)(ka + 16) * DIM + vd);
                #pragma unroll
                for (int e = 0; e < 4; ++e) {
                    int cc  = vd + e;                                  // d index
                    int col = (((kn >> 3) ^ ((cc >> 3) & 7)) << 3) | (kn & 7);
                    ushort2 pr;
                    pr.x = (&va.x)[e];
                    pr.y = (&vb.x)[e];
                    *(ushort2*)&Vt[cc][col] = pr;
                }
            }
        }
        __syncthreads();   // B2: Kl/Vt visible

        // ---- S = Q K^T ----
        f32x4 s[4];
        __builtin_amdgcn_s_setprio(1);
        #pragma unroll
        for (int kc = 0; kc < 4; ++kc) {
            f32x4 acc = (f32x4){0.f, 0.f, 0.f, 0.f};
            #pragma unroll
            for (int dc = 0; dc < 4; ++dc) {
                bf16x8 kf = *(const bf16x8*)&Kl[kc * 16 + l15][dc * 32 + l4 * 8];
                acc = __builtin_amdgcn_mfma_f32_16x16x32_bf16(qf[dc], kf, acc, 0, 0, 0);
            }
            s[kc] = acc;
        }
        __builtin_amdgcn_s_setprio(0);

        // ---- scale + causal mask + online softmax ----
        const bool diag = (jt == qt);
        float rowmax[4];
        #pragma unroll
        for (int r = 0; r < 4; ++r) rowmax[r] = -INFINITY;
        #pragma unroll
        for (int kc = 0; kc < 4; ++kc) {
            int key = jt * 64 + kc * 16 + l15;
            #pragma unroll
            for (int r = 0; r < 4; ++r) {
                float sv = s[kc][r] * scale;
                if (diag) {
                    int qrow = qb0 + w * 16 + l4 * 4 + r;
                    if (key > qrow) sv = -INFINITY;
                }
                s[kc][r] = sv;
                rowmax[r] = fmaxf(rowmax[r], sv);
            }
        }
        #pragma unroll
        for (int r = 0; r < 4; ++r) {
            float x2 = rowmax[r];
            x2 = fmaxf(x2, __shfl_xor(x2, 1));
            x2 = fmaxf(x2, __shfl_xor(x2, 2));
            x2 = fmaxf(x2, __shfl_xor(x2, 4));
            x2 = fmaxf(x2, __shfl_xor(x2, 8));
            rowmax[r] = x2;
        }
        float alpha[4];
        #pragma unroll
        for (int r = 0; r < 4; ++r) {
            float mnew = fmaxf(mr[r], rowmax[r]);
            alpha[r]   = __expf(mr[r] - mnew);
            mr[r]      = mnew;
        }
        float rowsum[4] = {0.f, 0.f, 0.f, 0.f};
        #pragma unroll
        for (int kc = 0; kc < 4; ++kc)
            #pragma unroll
            for (int r = 0; r < 4; ++r) {
                float p = __expf(s[kc][r] - mr[r]);
                s[kc][r] = p;
                rowsum[r] += p;
            }
        #pragma unroll
        for (int r = 0; r < 4; ++r) {
            float x2 = rowsum[r];
            x2 += __shfl_xor(x2, 1);
            x2 += __shfl_xor(x2, 2);
            x2 += __shfl_xor(x2, 4);
            x2 += __shfl_xor(x2, 8);
            lr[r] = lr[r] * alpha[r] + x2;
        }
        #pragma unroll
        for (int df = 0; df < 8; ++df)
            #pragma unroll
            for (int r = 0; r < 4; ++r) o[df][r] *= alpha[r];

        __syncthreads();   // B3: all waves done reading Kl before Pl overwrite

        // ---- P -> Pl in pi-permuted layout: 4x ds_write_b64 ----
        #pragma unroll
        for (int r = 0; r < 4; ++r) {
            bf16x4 pk;
            #pragma unroll
            for (int kc = 0; kc < 4; ++kc) pk[kc] = (__bf16)s[kc][r];
            *(bf16x4*)&Pl[w][l4 * 4 + r][l15 * 4] = pk;
        }

        // ---- O += P V (both operands enumerate pi(k)) ----
        __builtin_amdgcn_s_setprio(1);
        #pragma unroll
        for (int pc = 0; pc < 2; ++pc) {
            bf16x8 pa = *(const bf16x8*)&Pl[w][l15][pc * 32 + l4 * 8];
            #pragma unroll
            for (int df = 0; df < 8; ++df) {
                int cc  = df * 16 + l15;
                int kch = (pc * 4 + l4) ^ ((cc >> 3) & 7);
                bf16x8 vf = *(const bf16x8*)&Vt[cc][kch * 8];
                o[df] = __builtin_amdgcn_mfma_f32_16x16x32_bf16(pa, vf, o[df], 0, 0, 0);
            }
        }
        __builtin_amdgcn_s_setprio(0);
    }

    if (!SPLIT || nch == 1) {
        float inv[4];
        #pragma unroll
        for (int r = 0; r < 4; ++r) inv[r] = 1.0f / lr[r];
        float* op = out + base;
        #pragma unroll
        for (int df = 0; df < 8; ++df)
            #pragma unroll
            for (int r = 0; r < 4; ++r) {
                int row = qb0 + w * 16 + l4 * 4 + r;
                op[(size_t)row * DIM + df * 16 + l15] = o[df][r] * inv[r];
            }
    } else {
        char* sp = part + (size_t)slot * SLOT_BYTES;
        float*  smp = (float*)sp;           // m[64]
        float*  slp = (float*)(sp + 256);   // l[64]
        __bf16* sop = (__bf16*)(sp + 512);  // O[64][128] bf16
        #pragma unroll
        for (int r = 0; r < 4; ++r) {
            int rl = w * 16 + l4 * 4 + r;
            if (l15 == 0) { smp[rl] = mr[r]; slp[rl] = lr[r]; }
        }
        #pragma unroll
        for (int df = 0; df < 8; ++df)
            #pragma unroll
            for (int r = 0; r < 4; ++r) {
                int rl = w * 16 + l4 * 4 + r;
                sop[(size_t)rl * 128 + df * 16 + l15] = (__bf16)o[df][r];
            }
    }
}

// ---------------------------------------------------------------------------
// Kernel 3: combine partials for qt >= CHUNK. Grid ((64-CHUNK)*4, B); each
// block does a 16-row quarter of one qt (R15-proven parallel form).
// ---------------------------------------------------------------------------
template <int CHUNK>
__global__ __launch_bounds__(256) void combine(
    const char* __restrict__ part, float* __restrict__ out)
{
    constexpr int TASKS = tasks_per_b(CHUNK);

    const int qt  = (blockIdx.x >> 2) + CHUNK;
    const int qr  = blockIdx.x & 3;          // row quarter
    const int b   = blockIdx.y;
    const int g   = qt / CHUNK;
    const int nch = g + 1;
    const int slot0 = b * TASKS + CHUNK * g * (g + 1) / 2 + (qt % CHUNK) * nch;

    const int t   = threadIdx.x;
    const int row = qr * 16 + (t >> 4);      // 0..63
    const int c0  = (t & 15) * 8;            // 8-col strip

    float M = -INFINITY;
    for (int c = 0; c < nch; ++c) {
        const char* sp = part + (size_t)(slot0 + c) * SLOT_BYTES;
        M = fmaxf(M, ((const float*)sp)[row]);
    }
    float L = 0.f;
    for (int c = 0; c < nch; ++c) {
        const char* sp = part + (size_t)(slot0 + c) * SLOT_BYTES;
        L += ((const float*)(sp + 256))[row] * __expf(((const float*)sp)[row] - M);
    }

    float acc[8];
    #pragma unroll
    for (int i = 0; i < 8; ++i) acc[i] = 0.f;
    for (int c = 0; c < nch; ++c) {
        const char* sp = part + (size_t)(slot0 + c) * SLOT_BYTES;
        float wgt = __expf(((const float*)sp)[row] - M);
        const __bf16* op = (const __bf16*)(sp + 512) + (size_t)row * 128 + c0;
        bf16x8 vv = *(const bf16x8*)op;
        #pragma unroll
        for (int j = 0; j < 8; ++j)
            acc[j] += wgt * (float)vv[j];
    }
    float invL = 1.0f / L;
    float* o = out + ((size_t)b * SEQ + (size_t)qt * 64 + row) * DIM + c0;
    float4 f0, f1;
    f0.x = acc[0] * invL; f0.y = acc[1] * invL;
    f0.z = acc[2] * invL; f0.w = acc[3] * invL;
    f1.x = acc[4] * invL; f1.y = acc[5] * invL;
    f1.z = acc[6] * invL; f1.w = acc[7] * invL;
    *(float4*)o = f0;
    *(float4*)(o + 4) = f1;
}

// ---------------------------------------------------------------------------
extern "C" void kernel_launch(void* const* d_in, const int* in_sizes, int n_in,
                              void* d_out, int out_size, void* d_ws, size_t ws_size,
                              hipStream_t stream) {
    const float* x  = (const float*)d_in[0];
    const float* Wq = (const float*)d_in[1];
    const float* Wk = (const float*)d_in[2];
    const float* Wv = (const float*)d_in[3];
    float* out = (float*)d_out;

    __bf16* qw = (__bf16*)d_ws;
    __bf16* kw = qw + (size_t)BATCH * SEQ * DIM;
    __bf16* vw = kw + (size_t)BATCH * SEQ * DIM;
    char*   part = (char*)d_ws + QKV_BYTES;

    qkv_proj<<<dim3(BATCH * SEQ / 64, 3), 256, 0, stream>>>(x, Wq, Wk, Wv, qw, kw, vw);

    if (ws_size >= QKV_BYTES + part_bytes(4)) {
        attn<true, 4><<<dim3(tasks_per_b(4), BATCH), 256, 0, stream>>>(qw, kw, vw, out, part);
        combine<4><<<dim3(60 * 4, BATCH), 256, 0, stream>>>(part, out);
    } else if (ws_size >= QKV_BYTES + part_bytes(8)) {
        attn<true, 8><<<dim3(tasks_per_b(8), BATCH), 256, 0, stream>>>(qw, kw, vw, out, part);
        combine<8><<<dim3(56 * 4, BATCH), 256, 0, stream>>>(part, out);
    } else {
        attn<false, 8><<<dim3(SEQ / 64, BATCH), 256, 0, stream>>>(qw, kw, vw, out, part);
    }
}